// Round 22
// baseline (47.791 us; speedup 1.0000x reference)
//
#include <hip/hip_runtime.h>
#include <hip/hip_bf16.h>
#include <stdint.h>

// C[4096,10532] = inputs[4096,256] @ concat(lut,queue)[10532,256]^T  (fp32 out)
// R22 = R18 + TRIPLE-buffered A (3 x 16 KB) + vmcnt(10) barrier:
// with R18's double buffer, the single in-order vmcnt counter caps stores
// riding across a barrier at ONE generation (the next wait must drain the
// A-loads that sit between store generations in the queue). Staging sub+2
// puts exactly {stores(s-1) 4, loads(s+2) 2, stores(s) 4} = 10 ops newer
// than loads(s+1) -> vmcnt(10) proves the loads landed while EIGHT stores
// (two generations) stay in flight and drain under compute.
// Count-exactness: first iter vmcnt(6) (no prior stores); tail iters issue
// a dummy re-stage so 2 loads are always in queue; bn==41 -> vmcnt(0).

#define M_DIM 4096
#define K_DIM 256
#define N_LUT 5532
#define N_Q   5000
#define N_DIM (N_LUT + N_Q)   // 10532
#define BN    256
#define NT_N  42              // ceil(10532/256)
#define N_PAD (NT_N * 256)    // 10752
#define NSTRIP 6              // m-strips; 128 subtiles of 32 rows split 21/22

typedef _Float16 f16x8 __attribute__((ext_vector_type(8)));
typedef float f32x4 __attribute__((ext_vector_type(4)));

__device__ __forceinline__ unsigned short f2h(float f) {
  union { _Float16 h; unsigned short u; } v;
  v.h = (_Float16)f;   // v_cvt_f16_f32, RNE
  return v.u;
}

// ---------------- convert fp32 -> f16 into workspace ----------------
__global__ __launch_bounds__(256) void convert_kernel(
    const float* __restrict__ inp, const float* __restrict__ lut,
    const float* __restrict__ que, unsigned short* __restrict__ Abf,
    unsigned short* __restrict__ Bbf) {
  const int AV = M_DIM * K_DIM / 4;  // 262144 float4s for A
  int i = blockIdx.x * 256 + threadIdx.x;  // grid sized exactly
  float4 x;
  unsigned short* dst;
  if (i < AV) {
    x = ((const float4*)inp)[i];
    dst = Abf + i * 4;
  } else {
    int e = (i - AV) * 4;          // element index in padded B
    int row = e >> 8;              // /256
    int col = e & 255;
    if (row < N_LUT)
      x = *(const float4*)(lut + (size_t)row * K_DIM + col);
    else if (row < N_DIM)
      x = *(const float4*)(que + (size_t)(row - N_LUT) * K_DIM + col);
    else
      x = make_float4(0.f, 0.f, 0.f, 0.f);
    dst = Bbf + e;
  }
  ushort4 o;
  o.x = f2h(x.x); o.y = f2h(x.y); o.z = f2h(x.z); o.w = f2h(x.w);
  *(ushort4*)dst = o;
}

// ---------------- GEMM: persistent-B-in-regs, streaming-A ----------------
#define GLDS16(gsrc, ldst)                                                  \
  __builtin_amdgcn_global_load_lds(                                         \
      (__attribute__((address_space(1))) void*)(gsrc),                      \
      (__attribute__((address_space(3))) void*)(ldst), 16, 0, 0)

__global__ __launch_bounds__(512, 2) void gemm_kernel(
    const unsigned short* __restrict__ A, const unsigned short* __restrict__ B,
    float* __restrict__ C) {
  // A: TRIPLE-buffered 32 rows x 256 k = 3 x 16 KiB (B lives in VGPRs)
  __shared__ __align__(16) unsigned short As[3][32 * 256];

  const int t = threadIdx.x;
  const int lane = t & 63;
  const int wave = t >> 6;         // 8 waves; wave w owns C-cols w*32..+32

  // bijective XCD-chunked swizzle (m204): nwg=252, q=31, r=4; bn-fast order
  const int bid = blockIdx.x;
  const int xcd = bid & 7, idx = bid >> 3;
  const int wg = ((xcd < 4) ? xcd * 32 : 128 + (xcd - 4) * 31) + idx;
  const int s = wg / NT_N;         // strip 0..5
  const int bn = wg % NT_N;        // bn-fast within strip
  const int bcol = bn * BN;
  const bool fullN = (bcol + BN <= N_DIM);  // false only for bn==41
  // strips: subtile counts 21,21,21,21,22,22 (sum 128)
  const int csub = 21 + (s >= 4 ? 1 : 0);
  const int sub0 = 21 * s + (s >= 5 ? 1 : 0);   // s=5 starts at 106
  const int row0 = sub0 * 32;

  const int lr = lane & 15;
  const int rsw = lane & 7;        // = row&7 for all fragment rows
  const int cq = lane >> 4;        // 0..3
  const int cc4 = cq * 4;

  // ---- persistent B fragments -> registers (64 VGPR) ----
  // breg[j][ks]: B-row = bcol + wave*32 + j*16 + lr, k = ks*32 + cq*8.
  // Bbf padded/zeroed to N_PAD rows -> bn==41 loads in-bounds.
  f16x8 breg[2][8];
#pragma unroll
  for (int j = 0; j < 2; ++j) {
    const unsigned short* brow =
        B + (size_t)(bcol + wave * 32 + j * 16 + lr) * K_DIM + cq * 8;
#pragma unroll
    for (int ks = 0; ks < 8; ++ks)
      breg[j][ks] = *(const f16x8*)(brow + ks * 32);
  }

  // ---- A staging geometry (rows of 256 f16 = 32 x 16B chunks) ----
  // swizzle: lds[row][c] = global[row][c ^ (row&7)]; staging thread t in
  // round r covers slot row = r*16 + (t>>5), chunk = t&31 -> fetch swizzled.
  const int srow = t >> 5;                        // 0..15 within round
  const int scs = (((t & 31) ^ (srow & 7)) * 8);  // swizzled col, elements
  const unsigned short* gaBase0 = A + (size_t)(row0 + srow) * K_DIM + scs;
  const int ldsRound = wave * 2 * 256;  // wave-uniform base per round (elems)

  // A subtile: 32 rows = 2 rounds of 16 (2 gload_lds per thread)
#define STAGE_A(buf, sub)                                                    \
  do {                                                                       \
    _Pragma("unroll") for (int r = 0; r < 2; ++r)                            \
      GLDS16(gaBase0 + ((size_t)(sub) * 32 + r * 16) * K_DIM,                \
             As[buf] + r * 16 * 256 + ldsRound);                             \
  } while (0)

  // prologue: stage subtiles 0 and 1 (4 loads); wait for subtile 0 only
  // (2 newer = loads(1)) then barrier.
  STAGE_A(0, 0);
  STAGE_A(1, 1);
  asm volatile("s_waitcnt vmcnt(2)" ::: "memory");
  asm volatile("s_barrier" ::: "memory");

  int cur = 0;                     // buffer holding subtile `sub`
#pragma unroll 1
  for (int sub = 0; sub < csub; ++sub) {
    // stage sub+2 into buffer (cur+2)%3 (the one freed by iter sub-1).
    // Tail iters re-stage csub-1 into that (unused) buffer as a DUMMY so
    // exactly 2 loads sit in the queue every iteration (count-exactness).
    {
      int nb = cur + 2; if (nb >= 3) nb -= 3;
      const int ssub = (sub + 2 < csub) ? sub + 2 : csub - 1;
      STAGE_A(nb, ssub);
    }
    __builtin_amdgcn_sched_barrier(0);  // pin loads ABOVE compute+stores

    f32x4 acc[2][2] = {};
#pragma unroll
    for (int ks = 0; ks < 8; ++ks) {           // K = 256 = 8 x 32
      const int ch = (ks * 4 + cq) ^ rsw;      // swizzled 16B chunk, 0..31
      f16x8 a[2];
#pragma unroll
      for (int i = 0; i < 2; ++i)
        a[i] = *(const f16x8*)&As[cur][(i * 16 + lr) * 256 + ch * 8];
      // swapped operands: C-row = i*16+lr, C-cols = j*16 + cc4 + reg
#pragma unroll
      for (int i = 0; i < 2; ++i)
#pragma unroll
        for (int j = 0; j < 2; ++j)
          acc[i][j] = __builtin_amdgcn_mfma_f32_16x16x32_f16(breg[j][ks], a[i],
                                                             acc[i][j], 0, 0, 0);
    }

    // 4 dwordx4 C-stores (newest in vmem queue; ride across the barrier)
#pragma unroll
    for (int i = 0; i < 2; ++i) {
      size_t rowBase = (size_t)(row0 + sub * 32 + i * 16 + lr) * N_DIM;
#pragma unroll
      for (int j = 0; j < 2; ++j) {
        int col = bcol + wave * 32 + j * 16 + cc4;
        if (col < N_DIM)           // N_DIM%4==0: granule fully valid
          *(f32x4*)&C[rowBase + col] = acc[i][j];
      }
    }

    if (sub + 1 < csub) {
      // need loads(sub+1) complete. Ops newer in this wave's vmem queue:
      //   sub==0: loads(2) 2 + stores(0) 4            -> vmcnt(6)
      //   sub>=1: stores(sub-1) 4 + loads 2 + stores 4 -> vmcnt(10)
      // (8 stores = two generations ride the barrier and drain under the
      //  next subtile's compute.)  bn==41: divergent store counts -> 0.
      if (fullN) {
        if (sub == 0)
          asm volatile("s_waitcnt vmcnt(6)" ::: "memory");
        else
          asm volatile("s_waitcnt vmcnt(10)" ::: "memory");
      } else {
        asm volatile("s_waitcnt vmcnt(0)" ::: "memory");
      }
      asm volatile("s_barrier" ::: "memory");
    }
    cur = (cur == 2) ? 0 : cur + 1;
  }
#undef STAGE_A
}

extern "C" void kernel_launch(void* const* d_in, const int* in_sizes, int n_in,
                              void* d_out, int out_size, void* d_ws, size_t ws_size,
                              hipStream_t stream) {
  const float* inp = (const float*)d_in[0];   // inputs [4096,256]
  // d_in[1] targets, d_in[2] gt_flag: unused by the forward similarity
  const float* lut = (const float*)d_in[3];   // [5532,256]
  const float* que = (const float*)d_in[4];   // [5000,256]
  float* C = (float*)d_out;                   // [4096,10532]

  unsigned short* Abf = (unsigned short*)d_ws;
  unsigned short* Bbf = Abf + (size_t)M_DIM * K_DIM;  // ~7.7 MB of ws

  const int conv_blocks = (M_DIM * K_DIM / 4 + N_PAD * K_DIM / 4) / 256;
  convert_kernel<<<conv_blocks, 256, 0, stream>>>(inp, lut, que, Abf, Bbf);

  gemm_kernel<<<NSTRIP * NT_N, 512, 0, stream>>>(Abf, Bbf, C);
}